// Round 6
// baseline (236.538 us; speedup 1.0000x reference)
//
#include <hip/hip_runtime.h>

// ---------------------------------------------------------------------------
// CustomAttention: cosine-sim MHA.  N=1024 seq, B=4 batch, C=1024, H=16, hd=64
// R11: proj/out reverted to R5 exact (three dbuf variants R8/R9/R10 all lost;
//      R5's 2-barrier BK=64 + 2 resident blocks/CU is the m97-structure local
//      ceiling).  flash rewritten: K/V are L2-resident (256KB/head, XCD-pinned)
//      -- fragments now loaded DIRECTLY from global into MFMA layout regs, no
//      K/V LDS staging, ZERO barriers (P_lds is wave-private).  Guide m169
//      precedent: dropping V-staging at S=1024 = +26%.  8 free-running
//      waves/CU hide L1/L2 hit latency; V loads issued before exp phase.
// ---------------------------------------------------------------------------

typedef _Float16 f16x8 __attribute__((ext_vector_type(8)));
typedef __fp16   h16x2 __attribute__((ext_vector_type(2)));
typedef float    f32x4 __attribute__((ext_vector_type(4)));

#define LOG2E 1.4426950408889634f
#define LOGMAX 4.6051702f   // log(100)

#define GLOAD16(g, l) \
    __builtin_amdgcn_global_load_lds((__attribute__((address_space(1))) void*)(g), \
                                     (__attribute__((address_space(3))) void*)(l), 16, 0, 0)

__device__ __forceinline__ unsigned short f2h(float x) {
    union { _Float16 h; unsigned short u; } cv;
    cv.h = (_Float16)x;
    return cv.u;
}

// ---- fp32 -> fp16 convert, all 5 tensors in one launch ----
__global__ __launch_bounds__(256) void cvt_all(
    const float* __restrict__ q, const float* __restrict__ k,
    const float* __restrict__ v, const float* __restrict__ w,
    const float* __restrict__ ow,
    unsigned short* __restrict__ qbf, unsigned short* __restrict__ kbf,
    unsigned short* __restrict__ vbf, unsigned short* __restrict__ wbf,
    unsigned short* __restrict__ owbf)
{
    int b = blockIdx.x;
    const float* src; unsigned short* dst; int idx;
    if      (b < 4096)  { src = q;  dst = qbf;  idx = b; }
    else if (b < 8192)  { src = k;  dst = kbf;  idx = b - 4096; }
    else if (b < 12288) { src = v;  dst = vbf;  idx = b - 8192; }
    else if (b < 15360) { src = w;  dst = wbf;  idx = b - 12288; }
    else                { src = ow; dst = owbf; idx = b - 15360; }
    int i = idx * 256 + threadIdx.x;
    float4 val = ((const float4*)src)[i];
    ushort4 o;
    o.x = f2h(val.x); o.y = f2h(val.y); o.z = f2h(val.z); o.w = f2h(val.w);
    ((ushort4*)dst)[i] = o;
}

// ---- projection GEMM + fused l2norm epilogue (R5 exact) ----
__global__ __launch_bounds__(256) void proj_gemm(
    const unsigned short* __restrict__ qbf, const unsigned short* __restrict__ kbf,
    const unsigned short* __restrict__ vbf, const unsigned short* __restrict__ wbf,
    const float* __restrict__ bias, const float* __restrict__ lsc,
    unsigned short* __restrict__ qn, unsigned short* __restrict__ kn,
    unsigned short* __restrict__ vT)
{
    __shared__ __align__(16) unsigned short AsmF[128 * 64];
    __shared__ __align__(16) unsigned short BsmF[128 * 64];
    int tid = threadIdx.x;
    int lane = tid & 63, wave = tid >> 6;
    int lr = lane & 15, lq = lane >> 4;
    int wr = wave >> 1, wc = wave & 1;

    int lin = blockIdx.x;
    int xcd = lin & 7, s = lin >> 3;
    int xt = s & 7, yy = (s >> 3) & 3, z = s >> 5;
    int m0 = (xcd * 4 + yy) * 128, n0 = xt * 128;

    const unsigned short* A = (z == 0) ? qbf : (z == 1) ? kbf : vbf;
    const unsigned short* W = wbf + (size_t)z * 1024 * 1024;

    int rl = lane >> 3;
    int cg = ((lane & 7) ^ rl) << 3;                     // halves
    const unsigned short* gA = A + (size_t)(m0 + wave * 32 + rl) * 1024 + cg;
    const unsigned short* gB = W + (size_t)(n0 + wave * 32 + rl) * 1024 + cg;
    unsigned short* lA = &AsmF[wave * 32 * 64];
    unsigned short* lB = &BsmF[wave * 32 * 64];

    int swz = lr & 7;
    int c0 = (lq ^ swz) << 3;
    int c1 = ((lq ^ 4) ^ swz) << 3;

    f32x4 acc[4][4];
    for (int i = 0; i < 4; i++) for (int j = 0; j < 4; j++) acc[i][j] = (f32x4){0.f, 0.f, 0.f, 0.f};

    for (int ki = 0; ki < 16; ++ki) {
        for (int j = 0; j < 4; ++j) {
            GLOAD16(gA + ki * 64 + j * 8192, lA + j * 512);
            GLOAD16(gB + ki * 64 + j * 8192, lB + j * 512);
        }
        __syncthreads();
        for (int kc = 0; kc < 2; ++kc) {
            int co = kc ? c1 : c0;
            f16x8 af[4], bfr[4];
            for (int mi = 0; mi < 4; ++mi) af[mi]  = *(const f16x8*)&AsmF[(wr * 64 + mi * 16 + lr) * 64 + co];
            for (int ni = 0; ni < 4; ++ni) bfr[ni] = *(const f16x8*)&BsmF[(wc * 64 + ni * 16 + lr) * 64 + co];
            for (int mi = 0; mi < 4; ++mi)
                for (int ni = 0; ni < 4; ++ni)
                    acc[mi][ni] = __builtin_amdgcn_mfma_f32_16x16x32_f16(af[mi], bfr[ni], acc[mi][ni], 0, 0, 0);
        }
        __syncthreads();
    }

    int h = (n0 >> 6) + wc;
    float bv[4];
    for (int ni = 0; ni < 4; ++ni) bv[ni] = bias[z * 1024 + n0 + wc * 64 + ni * 16 + lr];
    for (int mi = 0; mi < 4; ++mi)
        for (int ni = 0; ni < 4; ++ni)
            for (int r = 0; r < 4; ++r) acc[mi][ni][r] += bv[ni];

    float lsfac = __expf(fminf(lsc[h], LOGMAX)) * LOG2E;

    for (int mi = 0; mi < 4; ++mi)
        for (int r = 0; r < 4; ++r) {
            int row = m0 + wr * 64 + mi * 16 + lq * 4 + r;   // m = n*4 + b
            int n = row >> 2, b = row & 3;
            int bh = b * 16 + h;
            if (z < 2) {
                float ss = 0.f;
                for (int ni = 0; ni < 4; ++ni) ss += acc[mi][ni][r] * acc[mi][ni][r];
                for (int off = 1; off < 16; off <<= 1) ss += __shfl_xor(ss, off);
                float scale = 1.0f / fmaxf(sqrtf(ss), 1e-12f);
                if (z == 0) scale *= lsfac;
                unsigned short* dst = (z == 0) ? qn : kn;
                for (int ni = 0; ni < 4; ++ni)
                    dst[(size_t)bh * 65536 + (size_t)n * 64 + ni * 16 + lr] = f2h(acc[mi][ni][r] * scale);
            } else {
                for (int ni = 0; ni < 4; ++ni)
                    vT[(size_t)bh * 65536 + (size_t)(ni * 16 + lr) * 1024 + n] = f2h(acc[mi][ni][r]);
            }
        }
}

// ---- flash attention: 128 q-rows/block, 2 q-groups per wave ----
// R11: K/V fragments loaded directly from global (L1/L2-hit; K/V is 256KB
// per head, XCD-pinned by the block swizzle).  No K/V LDS, no barriers.
// P_lds is wave-private (lgkm ordering only).
__global__ __launch_bounds__(256) void flash_kernel(
    const unsigned short* __restrict__ qn, const unsigned short* __restrict__ kn,
    const unsigned short* __restrict__ vT, const float* __restrict__ lsc,
    unsigned short* __restrict__ xb)
{
    __shared__ __align__(16) unsigned short P_lds[4][2][16][72]; // [wave][grp][qrow][kpos]
    int tid = threadIdx.x;
    int lane = tid & 63, wave = tid >> 6;
    int lr = lane & 15, lq = lane >> 4;

    int lin = blockIdx.x;
    int xcd = lin & 7, s = lin >> 3;
    int qt = s & 7, bh = xcd * 8 + (s >> 3);
    int q0 = qt * 128;

    // static softmax offset folded into QK accumulator init
    float off = __expf(fminf(lsc[bh & 15], LOGMAX)) * LOG2E - 12.0f;
    f32x4 initv = (f32x4){-off, -off, -off, -off};

    f16x8 qf[2][2];   // [group][kc]  B-frag: Q[qrow][d]
    for (int g = 0; g < 2; ++g)
        for (int kc = 0; kc < 2; ++kc)
            qf[g][kc] = *(const f16x8*)(qn + (size_t)bh * 65536 +
                          (size_t)(q0 + g * 64 + wave * 16 + lr) * 64 + kc * 32 + lq * 8);

    // fragment base pointers (MFMA lane layout = plain row slices)
    const unsigned short* Kb = kn + (size_t)bh * 65536 + (size_t)lr * 64 + lq * 8;
    const unsigned short* Vb = vT + (size_t)bh * 65536 + (size_t)lr * 1024 + lq * 8;

    f32x4 o[2][4];    // [group][nt]  O^T[d][qrow]
    for (int g = 0; g < 2; ++g) for (int i = 0; i < 4; i++) o[g][i] = (f32x4){0.f, 0.f, 0.f, 0.f};
    float lsum[2] = {0.f, 0.f};

    for (int kt = 0; kt < 16; ++kt) {
        // K fragments: rows kt*64 + ct*16 + lr, d-chunk kc*32 + lq*8
        f16x8 kf[2][4];
        for (int ct = 0; ct < 4; ++ct)
            for (int kc = 0; kc < 2; ++kc)
                kf[kc][ct] = *(const f16x8*)(Kb + kt * 4096 + ct * 1024 + kc * 32);

        // S^T = K Q^T - off : one K-frag feeds both q-groups
        f32x4 sc[2][4];
        __builtin_amdgcn_s_setprio(1);
        for (int ct = 0; ct < 4; ++ct)
            for (int kc = 0; kc < 2; ++kc)
                for (int g = 0; g < 2; ++g)
                    sc[g][ct] = __builtin_amdgcn_mfma_f32_16x16x32_f16(
                        kf[kc][ct], qf[g][kc], kc == 0 ? initv : sc[g][ct], 0, 0, 0);
        __builtin_amdgcn_s_setprio(0);

        // V fragments issued now; they land while exp/pack runs
        f16x8 vf[2][4];
        for (int nt = 0; nt < 4; ++nt)
            for (int kc = 0; kc < 2; ++kc)
                vf[kc][nt] = *(const f16x8*)(Vb + nt * 16384 + kt * 64 + kc * 32);

        // p = exp2(sc); per-lane l accumulate; pack to wave/group-private LDS
        for (int g = 0; g < 2; ++g)
            for (int ct = 0; ct < 4; ++ct) {
                float p0 = __builtin_amdgcn_exp2f(sc[g][ct][0]);
                float p1 = __builtin_amdgcn_exp2f(sc[g][ct][1]);
                float p2 = __builtin_amdgcn_exp2f(sc[g][ct][2]);
                float p3 = __builtin_amdgcn_exp2f(sc[g][ct][3]);
                lsum[g] += (p0 + p1) + (p2 + p3);
                union { h16x2 h[2]; ushort4 u; } pw;
                pw.h[0] = __builtin_amdgcn_cvt_pkrtz(p0, p1);
                pw.h[1] = __builtin_amdgcn_cvt_pkrtz(p2, p3);
                *(ushort4*)&P_lds[wave][g][lr][ct * 16 + lq * 4] = pw.u;
            }

        // O^T += V^T @ P^T : one V-frag feeds both groups
        f16x8 pf[2][2];
        for (int g = 0; g < 2; ++g)
            for (int kc = 0; kc < 2; ++kc)
                pf[g][kc] = *(const f16x8*)&P_lds[wave][g][lr][kc * 32 + lq * 8];
        __builtin_amdgcn_s_setprio(1);
        for (int nt = 0; nt < 4; ++nt)
            for (int kc = 0; kc < 2; ++kc)
                for (int g = 0; g < 2; ++g)
                    o[g][nt] = __builtin_amdgcn_mfma_f32_16x16x32_f16(
                        vf[kc][nt], pf[g][kc], o[g][nt], 0, 0, 0);
        __builtin_amdgcn_s_setprio(0);
    }

    int b = bh >> 4, h = bh & 15;
    for (int g = 0; g < 2; ++g) {
        float ls = lsum[g];
        ls += __shfl_xor(ls, 16);
        ls += __shfl_xor(ls, 32);
        float inv = 1.0f / ls;
        size_t m = (size_t)(q0 + g * 64 + wave * 16 + lr) * 4 + b;
        for (int nt = 0; nt < 4; ++nt) {
            ushort4 w;
            w.x = f2h(o[g][nt][0] * inv); w.y = f2h(o[g][nt][1] * inv);
            w.z = f2h(o[g][nt][2] * inv); w.w = f2h(o[g][nt][3] * inv);
            *(ushort4*)(xb + m * 1024 + h * 64 + nt * 16 + lq * 4) = w;
        }
    }
}

// ---- output GEMM: out(4096x1024) = X @ out_w^T + out_b;  128x64 tiles ----
// (R5 exact)
__global__ __launch_bounds__(256) void out_gemm(
    const unsigned short* __restrict__ xb, const unsigned short* __restrict__ owbf,
    const float* __restrict__ bias, float* __restrict__ outp)
{
    __shared__ __align__(16) unsigned short AsmF[128 * 64];
    __shared__ __align__(16) unsigned short BsmF[64 * 64];
    int tid = threadIdx.x;
    int lane = tid & 63, wave = tid >> 6;
    int lr = lane & 15, lq = lane >> 4;

    int lin = blockIdx.x;
    int xcd = lin & 7, s = lin >> 3;
    int xt = s & 15, yy = s >> 4;
    int m0 = (xcd * 4 + yy) * 128, n0 = xt * 64;

    int rl = lane >> 3;
    int cg = ((lane & 7) ^ rl) << 3;
    const unsigned short* gA = xb   + (size_t)(m0 + wave * 32 + rl) * 1024 + cg;
    const unsigned short* gB = owbf + (size_t)(n0 + wave * 16 + rl) * 1024 + cg;
    unsigned short* lA = &AsmF[wave * 32 * 64];
    unsigned short* lB = &BsmF[wave * 16 * 64];
    int swz = lr & 7;
    int c0 = (lq ^ swz) << 3;
    int c1 = ((lq ^ 4) ^ swz) << 3;

    f32x4 acc[2][4];
    for (int i = 0; i < 2; i++) for (int j = 0; j < 4; j++) acc[i][j] = (f32x4){0.f, 0.f, 0.f, 0.f};

    for (int ki = 0; ki < 16; ++ki) {
        for (int j = 0; j < 4; ++j)
            GLOAD16(gA + ki * 64 + j * 8192, lA + j * 512);
        for (int j = 0; j < 2; ++j)
            GLOAD16(gB + ki * 64 + j * 8192, lB + j * 512);
        __syncthreads();
        for (int kc = 0; kc < 2; ++kc) {
            int co = kc ? c1 : c0;
            f16x8 af[2], bfr[4];
            for (int mi = 0; mi < 2; ++mi) af[mi]  = *(const f16x8*)&AsmF[(wave * 32 + mi * 16 + lr) * 64 + co];
            for (int ni = 0; ni < 4; ++ni) bfr[ni] = *(const f16x8*)&BsmF[(ni * 16 + lr) * 64 + co];
            for (int mi = 0; mi < 2; ++mi)
                for (int ni = 0; ni < 4; ++ni)
                    acc[mi][ni] = __builtin_amdgcn_mfma_f32_16x16x32_f16(af[mi], bfr[ni], acc[mi][ni], 0, 0, 0);
        }
        __syncthreads();
    }
    for (int mi = 0; mi < 2; ++mi)
        for (int ni = 0; ni < 4; ++ni)
            for (int r = 0; r < 4; ++r) {
                int row = m0 + wave * 32 + mi * 16 + lq * 4 + r;
                int col = n0 + ni * 16 + lr;
                outp[(size_t)row * 1024 + col] = acc[mi][ni][r] + bias[col];
            }
}

extern "C" void kernel_launch(void* const* d_in, const int* in_sizes, int n_in,
                              void* d_out, int out_size, void* d_ws, size_t ws_size,
                              hipStream_t stream) {
    const float* query = (const float*)d_in[0];
    const float* key   = (const float*)d_in[1];
    const float* value = (const float*)d_in[2];
    const float* ipw   = (const float*)d_in[3];
    const float* ipb   = (const float*)d_in[4];
    const float* lsc   = (const float*)d_in[5];
    const float* ow    = (const float*)d_in[6];
    const float* ob    = (const float*)d_in[7];
    float* outp = (float*)d_out;

    char* ws = (char*)d_ws;
    unsigned short* qbf  = (unsigned short*)(ws);               // 8 MB fp16 query
    unsigned short* kbf  = (unsigned short*)(ws + 8388608);     // 8 MB
    unsigned short* vbf  = (unsigned short*)(ws + 16777216);    // 8 MB
    unsigned short* wbf  = (unsigned short*)(ws + 25165824);    // 6 MB in_proj_w
    unsigned short* owbf = (unsigned short*)(ws + 31457280);    // 2 MB out_w
    unsigned short* qn   = (unsigned short*)(ws + 33554432);    // 8 MB normalized q (bh,n,d)
    unsigned short* kn   = (unsigned short*)(ws + 41943040);    // 8 MB normalized k
    unsigned short* vT   = (unsigned short*)(ws + 50331648);    // 8 MB v^T (bh,d,n)
    unsigned short* xbuf = (unsigned short*)(ws + 58720256);    // 8 MB attn out (m, c) row-major

    cvt_all<<<16384, 256, 0, stream>>>(query, key, value, ipw, ow,
                                       qbf, kbf, vbf, wbf, owbf);
    proj_gemm<<<768, 256, 0, stream>>>(qbf, kbf, vbf, wbf, ipb, lsc, qn, kn, vT);
    flash_kernel<<<512, 256, 0, stream>>>(qn, kn, vT, lsc, xbuf);
    out_gemm<<<512, 256, 0, stream>>>(xbuf, owbf, ob, outp);
}

// Round 7
// 202.000 us; speedup vs baseline: 1.1710x; 1.1710x over previous
//
#include <hip/hip_runtime.h>

// ---------------------------------------------------------------------------
// CustomAttention: cosine-sim MHA.  N=1024 seq, B=4 batch, C=1024, H=16, hd=64
// R12: R11 post-mortem -- direct-global K/V killed inter-wave sharing (8x L1
//      traffic), flash 44->67.  Reverted.  New theory: flash is LATENCY-bound
//      with GRID-limited occupancy (17.7%, 2 blocks/CU, nothing saturated).
//      Fix occupancy instead of pipeline: 64 q-rows/block, grid 1024 = 4
//      independent blocks/CU (16 waves/CU); independent blocks overlap each
//      other's barrier drains (m114) -- no dbuf needed, single-buffer K/V
//      keeps LDS at 25.4KB.  2-q-group sharing dropped (measured +0.2us when
//      added).  proj/out/cvt = round-2 exact (best-measured 203.8).
// ---------------------------------------------------------------------------

typedef _Float16 f16x8 __attribute__((ext_vector_type(8)));
typedef __fp16   h16x2 __attribute__((ext_vector_type(2)));
typedef float    f32x4 __attribute__((ext_vector_type(4)));

#define LOG2E 1.4426950408889634f
#define LOGMAX 4.6051702f   // log(100)

#define GLOAD16(g, l) \
    __builtin_amdgcn_global_load_lds((__attribute__((address_space(1))) void*)(g), \
                                     (__attribute__((address_space(3))) void*)(l), 16, 0, 0)

__device__ __forceinline__ unsigned short f2h(float x) {
    union { _Float16 h; unsigned short u; } cv;
    cv.h = (_Float16)x;
    return cv.u;
}

// ---- fp32 -> fp16 convert, all 5 tensors in one launch ----
__global__ __launch_bounds__(256) void cvt_all(
    const float* __restrict__ q, const float* __restrict__ k,
    const float* __restrict__ v, const float* __restrict__ w,
    const float* __restrict__ ow,
    unsigned short* __restrict__ qbf, unsigned short* __restrict__ kbf,
    unsigned short* __restrict__ vbf, unsigned short* __restrict__ wbf,
    unsigned short* __restrict__ owbf)
{
    int b = blockIdx.x;
    const float* src; unsigned short* dst; int idx;
    if      (b < 4096)  { src = q;  dst = qbf;  idx = b; }
    else if (b < 8192)  { src = k;  dst = kbf;  idx = b - 4096; }
    else if (b < 12288) { src = v;  dst = vbf;  idx = b - 8192; }
    else if (b < 15360) { src = w;  dst = wbf;  idx = b - 12288; }
    else                { src = ow; dst = owbf; idx = b - 15360; }
    int i = idx * 256 + threadIdx.x;
    float4 val = ((const float4*)src)[i];
    ushort4 o;
    o.x = f2h(val.x); o.y = f2h(val.y); o.z = f2h(val.z); o.w = f2h(val.w);
    ((ushort4*)dst)[i] = o;
}

// ---- projection GEMM + fused l2norm epilogue (R5 exact) ----
__global__ __launch_bounds__(256) void proj_gemm(
    const unsigned short* __restrict__ qbf, const unsigned short* __restrict__ kbf,
    const unsigned short* __restrict__ vbf, const unsigned short* __restrict__ wbf,
    const float* __restrict__ bias, const float* __restrict__ lsc,
    unsigned short* __restrict__ qn, unsigned short* __restrict__ kn,
    unsigned short* __restrict__ vT)
{
    __shared__ __align__(16) unsigned short AsmF[128 * 64];
    __shared__ __align__(16) unsigned short BsmF[128 * 64];
    int tid = threadIdx.x;
    int lane = tid & 63, wave = tid >> 6;
    int lr = lane & 15, lq = lane >> 4;
    int wr = wave >> 1, wc = wave & 1;

    int lin = blockIdx.x;
    int xcd = lin & 7, s = lin >> 3;
    int xt = s & 7, yy = (s >> 3) & 3, z = s >> 5;
    int m0 = (xcd * 4 + yy) * 128, n0 = xt * 128;

    const unsigned short* A = (z == 0) ? qbf : (z == 1) ? kbf : vbf;
    const unsigned short* W = wbf + (size_t)z * 1024 * 1024;

    int rl = lane >> 3;
    int cg = ((lane & 7) ^ rl) << 3;                     // halves
    const unsigned short* gA = A + (size_t)(m0 + wave * 32 + rl) * 1024 + cg;
    const unsigned short* gB = W + (size_t)(n0 + wave * 32 + rl) * 1024 + cg;
    unsigned short* lA = &AsmF[wave * 32 * 64];
    unsigned short* lB = &BsmF[wave * 32 * 64];

    int swz = lr & 7;
    int c0 = (lq ^ swz) << 3;
    int c1 = ((lq ^ 4) ^ swz) << 3;

    f32x4 acc[4][4];
    for (int i = 0; i < 4; i++) for (int j = 0; j < 4; j++) acc[i][j] = (f32x4){0.f, 0.f, 0.f, 0.f};

    for (int ki = 0; ki < 16; ++ki) {
        for (int j = 0; j < 4; ++j) {
            GLOAD16(gA + ki * 64 + j * 8192, lA + j * 512);
            GLOAD16(gB + ki * 64 + j * 8192, lB + j * 512);
        }
        __syncthreads();
        for (int kc = 0; kc < 2; ++kc) {
            int co = kc ? c1 : c0;
            f16x8 af[4], bfr[4];
            for (int mi = 0; mi < 4; ++mi) af[mi]  = *(const f16x8*)&AsmF[(wr * 64 + mi * 16 + lr) * 64 + co];
            for (int ni = 0; ni < 4; ++ni) bfr[ni] = *(const f16x8*)&BsmF[(wc * 64 + ni * 16 + lr) * 64 + co];
            for (int mi = 0; mi < 4; ++mi)
                for (int ni = 0; ni < 4; ++ni)
                    acc[mi][ni] = __builtin_amdgcn_mfma_f32_16x16x32_f16(af[mi], bfr[ni], acc[mi][ni], 0, 0, 0);
        }
        __syncthreads();
    }

    int h = (n0 >> 6) + wc;
    float bv[4];
    for (int ni = 0; ni < 4; ++ni) bv[ni] = bias[z * 1024 + n0 + wc * 64 + ni * 16 + lr];
    for (int mi = 0; mi < 4; ++mi)
        for (int ni = 0; ni < 4; ++ni)
            for (int r = 0; r < 4; ++r) acc[mi][ni][r] += bv[ni];

    float lsfac = __expf(fminf(lsc[h], LOGMAX)) * LOG2E;

    for (int mi = 0; mi < 4; ++mi)
        for (int r = 0; r < 4; ++r) {
            int row = m0 + wr * 64 + mi * 16 + lq * 4 + r;   // m = n*4 + b
            int n = row >> 2, b = row & 3;
            int bh = b * 16 + h;
            if (z < 2) {
                float ss = 0.f;
                for (int ni = 0; ni < 4; ++ni) ss += acc[mi][ni][r] * acc[mi][ni][r];
                for (int off = 1; off < 16; off <<= 1) ss += __shfl_xor(ss, off);
                float scale = 1.0f / fmaxf(sqrtf(ss), 1e-12f);
                if (z == 0) scale *= lsfac;
                unsigned short* dst = (z == 0) ? qn : kn;
                for (int ni = 0; ni < 4; ++ni)
                    dst[(size_t)bh * 65536 + (size_t)n * 64 + ni * 16 + lr] = f2h(acc[mi][ni][r] * scale);
            } else {
                for (int ni = 0; ni < 4; ++ni)
                    vT[(size_t)bh * 65536 + (size_t)(ni * 16 + lr) * 1024 + n] = f2h(acc[mi][ni][r]);
            }
        }
}

// ---- flash attention: 64 q-rows/block, grid 1024 = 4 blocks/CU ----
// Wave w covers q-rows q0 + w*16 + lr.  Single-buffered K/V (25.4KB LDS);
// inter-block overlap hides the per-block barrier drain.  XCD swizzle: xcd
// owns 8 heads x 16 q-tiles (all q-tiles of a head share that XCD's L2 K/V).
__global__ __launch_bounds__(256) void flash_kernel(
    const unsigned short* __restrict__ qn, const unsigned short* __restrict__ kn,
    const unsigned short* __restrict__ vT, const float* __restrict__ lsc,
    unsigned short* __restrict__ xb)
{
    __shared__ __align__(16) unsigned short K_flat[64 * 64];
    __shared__ __align__(16) unsigned short V_flat[64 * 64];     // [d][kpos]
    __shared__ __align__(16) unsigned short P_lds[4][16][72];    // [wave][qrow][kpos]
    int tid = threadIdx.x;
    int lane = tid & 63, wave = tid >> 6;
    int lr = lane & 15, lq = lane >> 4;

    int lin = blockIdx.x;
    int xcd = lin & 7, s = lin >> 3;            // s in [0,128)
    int qt = s & 15, bh = xcd * 8 + (s >> 4);
    int q0 = qt * 64;

    // static softmax offset folded into QK accumulator init
    float off = __expf(fminf(lsc[bh & 15], LOGMAX)) * LOG2E - 12.0f;
    f32x4 initv = (f32x4){-off, -off, -off, -off};

    f16x8 qf[2];   // [kc]  B-frag: Q[qrow][d]
    for (int kc = 0; kc < 2; ++kc)
        qf[kc] = *(const f16x8*)(qn + (size_t)bh * 65536 +
                      (size_t)(q0 + wave * 16 + lr) * 64 + kc * 32 + lq * 8);

    int rl = lane >> 3;
    int cg = ((lane & 7) ^ rl) << 3;
    const unsigned short* gK = kn + (size_t)bh * 65536 + (size_t)(wave * 16 + rl) * 64 + cg;
    const unsigned short* gV = vT + (size_t)bh * 65536 + (size_t)(wave * 16 + rl) * 1024 + cg;
    unsigned short* lK = &K_flat[wave * 16 * 64];
    unsigned short* lV = &V_flat[wave * 16 * 64];
    int swz = lr & 7;
    int c0 = (lq ^ swz) << 3;
    int c1 = ((lq ^ 4) ^ swz) << 3;

    f32x4 o[4];    // [nt]  O^T[d][qrow]
    for (int i = 0; i < 4; i++) o[i] = (f32x4){0.f, 0.f, 0.f, 0.f};
    float lsum = 0.f;

    for (int kt = 0; kt < 16; ++kt) {
        for (int j = 0; j < 2; ++j) {
            GLOAD16(gK + kt * 4096 + j * 512,  lK + j * 512);
            GLOAD16(gV + kt * 64  + j * 8192,  lV + j * 512);
        }
        __syncthreads();

        // S^T = K Q^T - off
        f32x4 sc[4];
        __builtin_amdgcn_s_setprio(1);
        for (int ct = 0; ct < 4; ++ct)
            for (int kc = 0; kc < 2; ++kc) {
                f16x8 kf = *(const f16x8*)&K_flat[(ct * 16 + lr) * 64 + (kc ? c1 : c0)];
                sc[ct] = __builtin_amdgcn_mfma_f32_16x16x32_f16(
                    kf, qf[kc], kc == 0 ? initv : sc[ct], 0, 0, 0);
            }
        __builtin_amdgcn_s_setprio(0);

        // p = exp2(sc); per-lane l accumulate; pack to wave-private LDS
        for (int ct = 0; ct < 4; ++ct) {
            float p0 = __builtin_amdgcn_exp2f(sc[ct][0]);
            float p1 = __builtin_amdgcn_exp2f(sc[ct][1]);
            float p2 = __builtin_amdgcn_exp2f(sc[ct][2]);
            float p3 = __builtin_amdgcn_exp2f(sc[ct][3]);
            lsum += (p0 + p1) + (p2 + p3);
            union { h16x2 h[2]; ushort4 u; } pw;
            pw.h[0] = __builtin_amdgcn_cvt_pkrtz(p0, p1);
            pw.h[1] = __builtin_amdgcn_cvt_pkrtz(p2, p3);
            *(ushort4*)&P_lds[wave][lr][ct * 16 + lq * 4] = pw.u;
        }

        // O^T += V^T @ P^T
        f16x8 pf[2];
        for (int kc = 0; kc < 2; ++kc)
            pf[kc] = *(const f16x8*)&P_lds[wave][lr][kc * 32 + lq * 8];
        __builtin_amdgcn_s_setprio(1);
        for (int nt = 0; nt < 4; ++nt)
            for (int kc = 0; kc < 2; ++kc) {
                f16x8 vf = *(const f16x8*)&V_flat[(nt * 16 + lr) * 64 + (kc ? c1 : c0)];
                o[nt] = __builtin_amdgcn_mfma_f32_16x16x32_f16(vf, pf[kc], o[nt], 0, 0, 0);
            }
        __builtin_amdgcn_s_setprio(0);
        __syncthreads();
    }

    int b = bh >> 4, h = bh & 15;
    float ls = lsum;
    ls += __shfl_xor(ls, 16);
    ls += __shfl_xor(ls, 32);
    float inv = 1.0f / ls;
    size_t m = (size_t)(q0 + wave * 16 + lr) * 4 + b;
    for (int nt = 0; nt < 4; ++nt) {
        ushort4 w;
        w.x = f2h(o[nt][0] * inv); w.y = f2h(o[nt][1] * inv);
        w.z = f2h(o[nt][2] * inv); w.w = f2h(o[nt][3] * inv);
        *(ushort4*)(xb + m * 1024 + h * 64 + nt * 16 + lq * 4) = w;
    }
}

// ---- output GEMM: out(4096x1024) = X @ out_w^T + out_b;  128x64 tiles ----
// (R5 exact)
__global__ __launch_bounds__(256) void out_gemm(
    const unsigned short* __restrict__ xb, const unsigned short* __restrict__ owbf,
    const float* __restrict__ bias, float* __restrict__ outp)
{
    __shared__ __align__(16) unsigned short AsmF[128 * 64];
    __shared__ __align__(16) unsigned short BsmF[64 * 64];
    int tid = threadIdx.x;
    int lane = tid & 63, wave = tid >> 6;
    int lr = lane & 15, lq = lane >> 4;

    int lin = blockIdx.x;
    int xcd = lin & 7, s = lin >> 3;
    int xt = s & 15, yy = s >> 4;
    int m0 = (xcd * 4 + yy) * 128, n0 = xt * 64;

    int rl = lane >> 3;
    int cg = ((lane & 7) ^ rl) << 3;
    const unsigned short* gA = xb   + (size_t)(m0 + wave * 32 + rl) * 1024 + cg;
    const unsigned short* gB = owbf + (size_t)(n0 + wave * 16 + rl) * 1024 + cg;
    unsigned short* lA = &AsmF[wave * 32 * 64];
    unsigned short* lB = &BsmF[wave * 16 * 64];
    int swz = lr & 7;
    int c0 = (lq ^ swz) << 3;
    int c1 = ((lq ^ 4) ^ swz) << 3;

    f32x4 acc[2][4];
    for (int i = 0; i < 2; i++) for (int j = 0; j < 4; j++) acc[i][j] = (f32x4){0.f, 0.f, 0.f, 0.f};

    for (int ki = 0; ki < 16; ++ki) {
        for (int j = 0; j < 4; ++j)
            GLOAD16(gA + ki * 64 + j * 8192, lA + j * 512);
        for (int j = 0; j < 2; ++j)
            GLOAD16(gB + ki * 64 + j * 8192, lB + j * 512);
        __syncthreads();
        for (int kc = 0; kc < 2; ++kc) {
            int co = kc ? c1 : c0;
            f16x8 af[2], bfr[4];
            for (int mi = 0; mi < 2; ++mi) af[mi]  = *(const f16x8*)&AsmF[(wave * 32 + mi * 16 + lr) * 64 + co];
            for (int ni = 0; ni < 4; ++ni) bfr[ni] = *(const f16x8*)&BsmF[(ni * 16 + lr) * 64 + co];
            for (int mi = 0; mi < 2; ++mi)
                for (int ni = 0; ni < 4; ++ni)
                    acc[mi][ni] = __builtin_amdgcn_mfma_f32_16x16x32_f16(af[mi], bfr[ni], acc[mi][ni], 0, 0, 0);
        }
        __syncthreads();
    }
    for (int mi = 0; mi < 2; ++mi)
        for (int ni = 0; ni < 4; ++ni)
            for (int r = 0; r < 4; ++r) {
                int row = m0 + wave * 32 + mi * 16 + lq * 4 + r;
                int col = n0 + ni * 16 + lr;
                outp[(size_t)row * 1024 + col] = acc[mi][ni][r] + bias[col];
            }
}

extern "C" void kernel_launch(void* const* d_in, const int* in_sizes, int n_in,
                              void* d_out, int out_size, void* d_ws, size_t ws_size,
                              hipStream_t stream) {
    const float* query = (const float*)d_in[0];
    const float* key   = (const float*)d_in[1];
    const float* value = (const float*)d_in[2];
    const float* ipw   = (const float*)d_in[3];
    const float* ipb   = (const float*)d_in[4];
    const float* lsc   = (const float*)d_in[5];
    const float* ow    = (const float*)d_in[6];
    const float* ob    = (const float*)d_in[7];
    float* outp = (float*)d_out;

    char* ws = (char*)d_ws;
    unsigned short* qbf  = (unsigned short*)(ws);               // 8 MB fp16 query
    unsigned short* kbf  = (unsigned short*)(ws + 8388608);     // 8 MB
    unsigned short* vbf  = (unsigned short*)(ws + 16777216);    // 8 MB
    unsigned short* wbf  = (unsigned short*)(ws + 25165824);    // 6 MB in_proj_w
    unsigned short* owbf = (unsigned short*)(ws + 31457280);    // 2 MB out_w
    unsigned short* qn   = (unsigned short*)(ws + 33554432);    // 8 MB normalized q (bh,n,d)
    unsigned short* kn   = (unsigned short*)(ws + 41943040);    // 8 MB normalized k
    unsigned short* vT   = (unsigned short*)(ws + 50331648);    // 8 MB v^T (bh,d,n)
    unsigned short* xbuf = (unsigned short*)(ws + 58720256);    // 8 MB attn out (m, c) row-major

    cvt_all<<<16384, 256, 0, stream>>>(query, key, value, ipw, ow,
                                       qbf, kbf, vbf, wbf, owbf);
    proj_gemm<<<768, 256, 0, stream>>>(qbf, kbf, vbf, wbf, ipb, lsc, qn, kn, vT);
    flash_kernel<<<1024, 256, 0, stream>>>(qn, kn, vT, lsc, xbuf);
    out_gemm<<<512, 256, 0, stream>>>(xbuf, owbf, ob, outp);
}